// Round 7
// baseline (805.366 us; speedup 1.0000x reference)
//
#include <hip/hip_runtime.h>
#include <math.h>

typedef unsigned short u16;
typedef __bf16 bf16x8 __attribute__((ext_vector_type(8)));
typedef float f32x4 __attribute__((ext_vector_type(4)));

#define T_TOK 4096
#define DIM   1024
#define HID   4096
#define NE    8
#define TOPK  3
#define NPAIR 12288   // T_TOK * TOPK

// prep grid layout: [0,1024) router | [1024,3072) w3 tiles | [3072,7168) w12 tiles
#define PREP_W3_BASE  1024
#define PREP_W12_BASE 3072
#define PREP_BLOCKS   7168

// ---------------- ws layout (bytes) ----------------
// ctrl ints: [0..7]=ecnt, [16..23]=efill
constexpr size_t OFF_CTRL = 0;
constexpr size_t OFF_XB   = 256;
constexpr size_t OFF_W12T = OFF_XB   + (size_t)T_TOK * DIM * 2;
constexpr size_t OFF_W3T  = OFF_W12T + (size_t)NE * 2 * HID * DIM * 2;
constexpr size_t OFF_HID  = OFF_W3T  + (size_t)NE * DIM * HID * 2;
constexpr size_t OFF_Y    = OFF_HID  + (size_t)NPAIR * HID * 2;
constexpr size_t OFF_PTOK = OFF_Y    + (size_t)NPAIR * DIM * 4;
constexpr size_t OFF_TE   = OFF_PTOK + (size_t)NPAIR * 4;
constexpr size_t OFF_TW   = OFF_TE   + (size_t)T_TOK * TOPK * 4;
constexpr size_t OFF_TS   = OFF_TW   + (size_t)T_TOK * TOPK * 4;

__device__ __forceinline__ u16 f2bf(float f) {
    unsigned u = __builtin_bit_cast(unsigned, f);
    u += 0x7fffu + ((u >> 16) & 1u);   // RNE
    return (u16)(u >> 16);
}

// async global->LDS DMA, 16B per lane; LDS dst = wave-uniform base + lane*16
__device__ __forceinline__ void ld_g2l(const u16* g, u16* l) {
    __builtin_amdgcn_global_load_lds((__attribute__((address_space(1))) unsigned*)(g),
                                     (__attribute__((address_space(3))) unsigned*)(l),
                                     16, 0, 0);
}

// raw sync primitives: raw s_barrier does NOT drain vmcnt (that's the point)
#define VMCNT(N) asm volatile("s_waitcnt vmcnt(" #N ")" ::: "memory")
#define LGKM0  asm volatile("s_waitcnt lgkmcnt(0)" ::: "memory")
#define SBAR   __builtin_amdgcn_s_barrier()
#define SCHED0 __builtin_amdgcn_sched_barrier(0)
#define PRIO1  __builtin_amdgcn_s_setprio(1)
#define PRIO0  __builtin_amdgcn_s_setprio(0)

// quarter staging macros (2 global_load_lds each)
#define STAGE_A02(dst) { ld_g2l(srcA[0], (dst) + (0 * 64 + wave * 8) * 64); \
                         ld_g2l(srcA[2], (dst) + (2 * 64 + wave * 8) * 64); }
#define STAGE_B01(dst) { ld_g2l(srcB[0], (dst) + 16384 + (0 * 64 + wave * 8) * 64); \
                         ld_g2l(srcB[1], (dst) + 16384 + (1 * 64 + wave * 8) * 64); }
#define STAGE_B23(dst) { ld_g2l(srcB[2], (dst) + 16384 + (2 * 64 + wave * 8) * 64); \
                         ld_g2l(srcB[3], (dst) + 16384 + (3 * 64 + wave * 8) * 64); }
#define STAGE_A13(dst) { ld_g2l(srcA[1], (dst) + (1 * 64 + wave * 8) * 64); \
                         ld_g2l(srcA[3], (dst) + (3 * 64 + wave * 8) * 64); }
#define ADV()          { _Pragma("unroll") \
                         for (int r_ = 0; r_ < 4; ++r_) { srcA[r_] += 64; srcB[r_] += 64; } }

// ---------------- transpose-cast 64k x 256n tile ----------------
// in [K][N] fp32 -> out [N][K] bf16. Reads: 1 KB contiguous per input row
// (16 x 64B sequential segments). Converts at LDS-write into transposed
// u16[256][72] tile (scatter writes, cost hidden under HBM). Writes: 128 B
// contiguous per output row, 16 rows x 128 B per store instruction.
__device__ __forceinline__ void tc_tile(const float* __restrict__ inp,
                                        u16* __restrict__ outp,
                                        int K, int N, int n0, int k0, int tid,
                                        u16 (*lt)[72]) {
    const int k = tid >> 2;            // 0..63 input row within tile
    const int cbase = (tid & 3) * 4;   // 0,4,8,12
    const float* row = inp + (size_t)(k0 + k) * N + n0;
#pragma unroll
    for (int j = 0; j < 16; ++j) {
        const int c = cbase + j * 16;
        float4 f = *(const float4*)(row + c);
        lt[c + 0][k] = f2bf(f.x);
        lt[c + 1][k] = f2bf(f.y);
        lt[c + 2][k] = f2bf(f.z);
        lt[c + 3][k] = f2bf(f.w);
    }
    __syncthreads();
    const int rg = tid >> 2;          // 0..63 out-row within group
    const int kc = (tid & 3) * 16;    // 0,16,32,48
#pragma unroll
    for (int g = 0; g < 4; ++g) {
        const int n = g * 64 + rg;
        u16* op = outp + (size_t)(n0 + n) * K + k0 + kc;
        *(uint4*)(op)     = *(const uint4*)(&lt[n][kc]);
        *(uint4*)(op + 8) = *(const uint4*)(&lt[n][kc + 8]);
    }
}

// ---------------- prep: router + w12 transpose + w3 transpose in ONE launch ----
__global__ __launch_bounds__(256) void prep_kernel(const float* __restrict__ x,
                                                   const float* __restrict__ rw,
                                                   const float* __restrict__ rb,
                                                   u16* __restrict__ xb,
                                                   int* __restrict__ tok_expert,
                                                   float* __restrict__ tok_w,
                                                   int* __restrict__ ctrl,
                                                   float* __restrict__ aux,
                                                   const float* __restrict__ w12,
                                                   u16* __restrict__ w12t,
                                                   const float* __restrict__ w3,
                                                   u16* __restrict__ w3t) {
    __shared__ __align__(16) u16 lt[256][72];   // 36 KB
    const int bid = blockIdx.x;
    const int tid = threadIdx.x;

    if (bid >= PREP_W12_BASE) {
        // w12: in [DIM][2H] fp32 -> out [2H][DIM] bf16.  K=DIM, N=2H.
        // per expert: k-tiles 16, n-tiles 32 -> 512 tiles
        const int b = bid - PREP_W12_BASE;
        const int z = b >> 9;
        const int r = b & 511;
        const int kt = r >> 5, nt = r & 31;
        tc_tile(w12 + (size_t)z * DIM * 2 * HID, w12t + (size_t)z * DIM * 2 * HID,
                DIM, 2 * HID, nt * 256, kt * 64, tid, lt);
        return;
    }
    if (bid >= PREP_W3_BASE) {
        // w3: in [HID][DIM] fp32 -> out [DIM][HID] bf16.  K=HID, N=DIM.
        // per expert: k-tiles 64, n-tiles 4 -> 256 tiles
        const int b = bid - PREP_W3_BASE;
        const int z = b >> 8;
        const int r = b & 255;
        const int kt = r >> 2, nt = r & 3;
        tc_tile(w3 + (size_t)z * HID * DIM, w3t + (size_t)z * HID * DIM,
                HID, DIM, nt * 256, kt * 64, tid, lt);
        return;
    }

    // ---- router (fused x->bf16 cast, block-level atomics) ----
    int* hist = (int*)&lt[0][0];
    float* auxsh = (float*)&lt[2][0];
    if (tid < NE) hist[tid] = 0;
    if (tid == NE) auxsh[0] = 0.f;
    __syncthreads();

    const int wave = tid >> 6, lane = tid & 63;
    const int t = bid * 4 + wave;
    const float* xr = x + (size_t)t * DIM;
    u16* xbr = xb + (size_t)t * DIM;

    float p[NE];
#pragma unroll
    for (int e = 0; e < NE; e++) p[e] = 0.f;
#pragma unroll
    for (int q = 0; q < 4; ++q) {
        const int d = q * 256 + lane * 4;
        float4 f = *(const float4*)(xr + d);
        uint2 v;
        v.x = (unsigned)f2bf(f.x) | ((unsigned)f2bf(f.y) << 16);
        v.y = (unsigned)f2bf(f.z) | ((unsigned)f2bf(f.w) << 16);
        *(uint2*)(xbr + d) = v;
#pragma unroll
        for (int e = 0; e < NE; e++) {
            float4 w = *(const float4*)(rw + e * DIM + d);
            p[e] += f.x * w.x + f.y * w.y + f.z * w.z + f.w * w.w;
        }
    }
#pragma unroll
    for (int e = 0; e < NE; e++) {
#pragma unroll
        for (int off = 32; off; off >>= 1) p[e] += __shfl_down(p[e], off, 64);
    }
    if (lane == 0) {
        float s[NE]; float auxs = 0.f;
#pragma unroll
        for (int e = 0; e < NE; e++) {
            float lg = p[e] + rb[e];
            auxs += lg * lg;
            s[e] = 1.f / (1.f + __expf(-lg));
        }
        atomicAdd(auxsh, auxs);
        unsigned mask = 0; float wsum = 0.f;
        int idxs[TOPK]; float vals[TOPK];
        for (int k = 0; k < TOPK; k++) {
            float best = -1.f; int bi = 0;
            for (int e = 0; e < NE; e++)
                if (!((mask >> e) & 1u) && s[e] > best) { best = s[e]; bi = e; }
            mask |= 1u << bi; idxs[k] = bi; vals[k] = best; wsum += best;
        }
        wsum += 1e-6f;
        for (int k = 0; k < TOPK; k++) {
            tok_expert[t * TOPK + k] = idxs[k];
            tok_w[t * TOPK + k] = vals[k] / wsum;
            atomicAdd(&hist[idxs[k]], 1);
        }
    }
    __syncthreads();
    if (tid < NE) { int h = hist[tid]; if (h) atomicAdd(&ctrl[tid], h); }
    if (tid == NE) atomicAdd(aux, auxsh[0] * (0.01f / 32768.0f));
}

// assign: two-level atomics — per-block LDS histogram, one global reservation
// per expert per block. Slot order within an expert is a permutation;
// all consumers are permutation-invariant.
__global__ __launch_bounds__(256) void assign_kernel(const int* __restrict__ tok_expert,
                                                     int* __restrict__ ctrl,
                                                     int* __restrict__ pair_token,
                                                     int* __restrict__ tok_slot) {
    __shared__ int soff[NE];   // global expert start (prefix of counts)
    __shared__ int hist[NE];   // this block's per-expert count
    __shared__ int base[NE];   // this block's reserved base within expert
    const int tid = threadIdx.x;
    if (tid < NE) {
        int acc = 0;
        for (int i = 0; i < tid; ++i) acc += ctrl[i];
        soff[tid] = acc;
        hist[tid] = 0;
    }
    __syncthreads();
    const int t = blockIdx.x * blockDim.x + tid;
    int e[TOPK], p[TOPK];
#pragma unroll
    for (int k = 0; k < TOPK; k++) {
        e[k] = tok_expert[t * TOPK + k];
        p[k] = atomicAdd(&hist[e[k]], 1);
    }
    __syncthreads();
    if (tid < NE && hist[tid]) base[tid] = atomicAdd(&ctrl[16 + tid], hist[tid]);
    __syncthreads();
#pragma unroll
    for (int k = 0; k < TOPK; k++) {
        const int slot = soff[e[k]] + base[e[k]] + p[k];
        pair_token[slot] = t;
        tok_slot[t * TOPK + k] = slot;
    }
}

// ---------------- GEMM1: hidden = silu(x@w1)*(x@w2), gathered rows ----------------
// Round-2 schedule verbatim (best measured 236 us / MfmaUtil 41.5%): quarter staging,
// counted vmcnt 4/6/6, one barrier per phase, lgkm wall before each MFMA cluster.
__global__ __launch_bounds__(512, 2) void gemm1_kernel(const u16* __restrict__ xb,
                                                       const u16* __restrict__ w12t,
                                                       const int* __restrict__ pair_token,
                                                       const int* __restrict__ ctrl,
                                                       u16* __restrict__ hidden) {
    const int e = blockIdx.z;
    const int cnt = ctrl[e];
    if ((int)blockIdx.y * 256 >= cnt) return;
    int off = 0;
    for (int i = 0; i < e; ++i) off += ctrl[i];
    const int rowbase = off + blockIdx.y * 256;
    const int rowend = off + cnt;
    const int n0 = blockIdx.x * 128;   // col base within each half

    extern __shared__ __align__(16) u16 lds[];   // 2 slots x 32768 u16

    const int tid = threadIdx.x;
    const int wave = tid >> 6, lane = tid & 63;
    const int srow = tid >> 3;                       // 0..63 row-in-round
    const int scol = ((tid & 7) ^ (srow & 7)) * 8;   // pre-swizzled global col

    const u16* srcA[4];
    const u16* srcB[4];
#pragma unroll
    for (int r = 0; r < 4; ++r) {
        int sr = rowbase + r * 64 + srow;
        int tok = (sr < rowend) ? pair_token[sr] : 0;
        srcA[r] = xb + (size_t)tok * DIM + scol;
    }
#pragma unroll
    for (int r = 0; r < 2; ++r) {
        srcB[r]     = w12t + ((size_t)e * 2 * HID + n0 + r * 64 + srow) * DIM + scol; // w1
        srcB[r + 2] = srcB[r] + (size_t)HID * DIM;                                    // w2
    }

    const int wm = wave >> 2, wn = wave & 3;
    const int lrow = lane & 15, lq = lane >> 4, xm = lrow & 7;
    const int so0 = ((lq ^ xm) << 3);
    const int so1 = (((4 | lq) ^ xm) << 3);

    f32x4 acc0[8][2], acc1[8][2];
#pragma unroll
    for (int mf = 0; mf < 8; ++mf)
#pragma unroll
        for (int nf = 0; nf < 2; ++nf) { acc0[mf][nf] = (f32x4)0.f; acc1[mf][nf] = (f32x4)0.f; }

    // prologue: stage K-tile 0 in queue order [p0-set(4), p1-set(2), p2-set(2)]
    STAGE_A02(lds); STAGE_B01(lds);
    STAGE_B23(lds);
    STAGE_A13(lds);
    ADV();

    const int NT = DIM / 64;   // 16
    for (int kt = 0; kt < NT; ++kt) {
        u16* cur = lds + (kt & 1) * 32768;
        u16* nxt = lds + ((kt & 1) ^ 1) * 32768;
        const u16* sA = cur;
        const u16* sB = cur + 16384;
        const bool notlast = (kt < NT - 1);

        bf16x8 a[4][2], b0[2][2], b1[2][2];
        // ---- phase 0: wait p0-set; read A-lo + B0; issue next p0-set ----
        VMCNT(4); SBAR; SCHED0;
#pragma unroll
        for (int mf = 0; mf < 4; ++mf) {
            const u16* base = sA + (wm * 128 + mf * 16 + lrow) * 64;
            a[mf][0] = *(const bf16x8*)(base + so0);
            a[mf][1] = *(const bf16x8*)(base + so1);
        }
#pragma unroll
        for (int nf = 0; nf < 2; ++nf) {
            const u16* base = sB + (wn * 32 + nf * 16 + lrow) * 64;
            b0[nf][0] = *(const bf16x8*)(base + so0);
            b0[nf][1] = *(const bf16x8*)(base + so1);
        }
        if (notlast) { STAGE_A02(nxt); STAGE_B01(nxt); }
        LGKM0; SCHED0;
        PRIO1;
#pragma unroll
        for (int mf = 0; mf < 4; ++mf)
#pragma unroll
            for (int nf = 0; nf < 2; ++nf) {
                acc0[mf][nf] = __builtin_amdgcn_mfma_f32_16x16x32_bf16(a[mf][0], b0[nf][0], acc0[mf][nf], 0, 0, 0);
                acc0[mf][nf] = __builtin_amdgcn_mfma_f32_16x16x32_bf16(a[mf][1], b0[nf][1], acc0[mf][nf], 0, 0, 0);
            }
        PRIO0;
        // ---- phase 1: wait p1-set; read B1; issue next p1-set ----
        if (notlast) { VMCNT(6); } else { VMCNT(2); }
        SBAR; SCHED0;
#pragma unroll
        for (int nf = 0; nf < 2; ++nf) {
            const u16* base = sB + 128 * 64 + (wn * 32 + nf * 16 + lrow) * 64;
            b1[nf][0] = *(const bf16x8*)(base + so0);
            b1[nf][1] = *(const bf16x8*)(base + so1);
        }
        if (notlast) STAGE_B23(nxt);
        LGKM0; SCHED0;
        PRIO1;
#pragma unroll
        for (int mf = 0; mf < 4; ++mf)
#pragma unroll
            for (int nf = 0; nf < 2; ++nf) {
                acc1[mf][nf] = __builtin_amdgcn_mfma_f32_16x16x32_bf16(a[mf][0], b1[nf][0], acc1[mf][nf], 0, 0, 0);
                acc1[mf][nf] = __builtin_amdgcn_mfma_f32_16x16x32_bf16(a[mf][1], b1[nf][1], acc1[mf][nf], 0, 0, 0);
            }
        PRIO0;
        // ---- phase 2: wait p2-set; read A-hi; issue next p2-set ----
        if (notlast) { VMCNT(6); } else { VMCNT(0); }
        SBAR; SCHED0;
#pragma unroll
        for (int mf = 0; mf < 4; ++mf) {
            const u16* base = sA + (wm * 128 + (mf + 4) * 16 + lrow) * 64;
            a[mf][0] = *(const bf16x8*)(base + so0);
            a[mf][1] = *(const bf16x8*)(base + so1);
        }
        if (notlast) { STAGE_A13(nxt); ADV(); }
        LGKM0; SCHED0;
        PRIO1;
#pragma unroll
        for (int mf = 0; mf < 4; ++mf)
#pragma unroll
            for (int nf = 0; nf < 2; ++nf) {
                acc1[mf + 4][nf] = __builtin_amdgcn_mfma_f32_16x16x32_bf16(a[mf][0], b1[nf][0], acc1[mf + 4][nf], 0, 0, 0);
                acc1[mf + 4][nf] = __builtin_amdgcn_mfma_f32_16x16x32_bf16(a[mf][1], b1[nf][1], acc1[mf + 4][nf], 0, 0, 0);
            }
        PRIO0;
        // ---- phase 3: no reads, no waits (reuse A-hi + B0) ----
        SBAR;
        PRIO1;
#pragma unroll
        for (int mf = 0; mf < 4; ++mf)
#pragma unroll
            for (int nf = 0; nf < 2; ++nf) {
                acc0[mf + 4][nf] = __builtin_amdgcn_mfma_f32_16x16x32_bf16(a[mf][0], b0[nf][0], acc0[mf + 4][nf], 0, 0, 0);
                acc0[mf + 4][nf] = __builtin_amdgcn_mfma_f32_16x16x32_bf16(a[mf][1], b0[nf][1], acc0[mf + 4][nf], 0, 0, 0);
            }
        PRIO0;
    }

#pragma unroll
    for (int mf = 0; mf < 8; ++mf) {
        const int gr0 = rowbase + wm * 128 + mf * 16 + lq * 4;
#pragma unroll
        for (int nf = 0; nf < 2; ++nf) {
            const int gc = n0 + wn * 32 + nf * 16 + lrow;
#pragma unroll
            for (int r = 0; r < 4; ++r) {
                const int gr = gr0 + r;
                if (gr < rowend) {
                    float x1 = acc0[mf][nf][r], x2 = acc1[mf][nf][r];
                    float h = x1 / (1.f + __expf(-x1)) * x2;
                    hidden[(size_t)gr * HID + gc] = f2bf(h);
                }
            }
        }
    }
}

// ---------------- GEMM2: y = hidden @ w3 ----------------
// 256x256 tile, BK=64, 8 waves (2Mx4N) — round-2 wall schedule:
// counted vmcnt 4/6/6, lgkm wall + setprio around each MFMA cluster.
__global__ __launch_bounds__(512, 2) void gemm2_kernel(const u16* __restrict__ hidden,
                                                       const u16* __restrict__ w3t,
                                                       const int* __restrict__ ctrl,
                                                       float* __restrict__ ybuf) {
    const int e = blockIdx.z;
    const int cnt = ctrl[e];
    if ((int)blockIdx.y * 256 >= cnt) return;
    int off = 0;
    for (int i = 0; i < e; ++i) off += ctrl[i];
    const int rowbase = off + blockIdx.y * 256;
    const int rowend = off + cnt;
    const int n0 = blockIdx.x * 256;

    extern __shared__ __align__(16) u16 lds[];

    const int tid = threadIdx.x;
    const int wave = tid >> 6, lane = tid & 63;
    const int srow = tid >> 3;
    const int scol = ((tid & 7) ^ (srow & 7)) * 8;

    const u16* srcA[4];
    const u16* srcB[4];
#pragma unroll
    for (int r = 0; r < 4; ++r) {
        int sr = rowbase + r * 64 + srow;
        if (sr > NPAIR - 1) sr = NPAIR - 1;
        srcA[r] = hidden + (size_t)sr * HID + scol;
        srcB[r] = w3t + ((size_t)e * DIM + n0 + r * 64 + srow) * HID + scol;
    }

    const int wm = wave >> 2, wn = wave & 3;
    const int lrow = lane & 15, lq = lane >> 4, xm = lrow & 7;
    const int so0 = ((lq ^ xm) << 3);
    const int so1 = (((4 | lq) ^ xm) << 3);

    f32x4 acc[8][4];
#pragma unroll
    for (int mf = 0; mf < 8; ++mf)
#pragma unroll
        for (int nf = 0; nf < 4; ++nf) acc[mf][nf] = (f32x4)0.f;

    STAGE_A02(lds); STAGE_B01(lds);
    STAGE_B23(lds);
    STAGE_A13(lds);
    ADV();

    const int NT = HID / 64;   // 64
    for (int kt = 0; kt < NT; ++kt) {
        u16* cur = lds + (kt & 1) * 32768;
        u16* nxt = lds + ((kt & 1) ^ 1) * 32768;
        const u16* sA = cur;
        const u16* sB = cur + 16384;
        const bool notlast = (kt < NT - 1);

        bf16x8 a[4][2], b[4][2];
        // ---- phase 0: wait p0-set; read A-lo + B[0..1]; issue next p0-set ----
        VMCNT(4); SBAR; SCHED0;
#pragma unroll
        for (int mf = 0; mf < 4; ++mf) {
            const u16* base = sA + (wm * 128 + mf * 16 + lrow) * 64;
            a[mf][0] = *(const bf16x8*)(base + so0);
            a[mf][1] = *(const bf16x8*)(base + so1);
        }
#pragma unroll
        for (int nf = 0; nf < 2; ++nf) {
            const u16* base = sB + (nf * 64 + wn * 16 + lrow) * 64;
            b[nf][0] = *(const bf16x8*)(base + so0);
            b[nf][1] = *(const bf16x8*)(base + so1);
        }
        if (notlast) { STAGE_A02(nxt); STAGE_B01(nxt); }
        LGKM0; SCHED0;
        PRIO1;
#pragma unroll
        for (int mf = 0; mf < 4; ++mf)
#pragma unroll
            for (int nf = 0; nf < 2; ++nf) {
                acc[mf][nf] = __builtin_amdgcn_mfma_f32_16x16x32_bf16(a[mf][0], b[nf][0], acc[mf][nf], 0, 0, 0);
                acc[mf][nf] = __builtin_amdgcn_mfma_f32_16x16x32_bf16(a[mf][1], b[nf][1], acc[mf][nf], 0, 0, 0);
            }
        PRIO0;
        // ---- phase 1: wait p1-set; read B[2..3]; issue next p1-set ----
        if (notlast) { VMCNT(6); } else { VMCNT(2); }
        SBAR; SCHED0;
#pragma unroll
        for (int nf = 2; nf < 4; ++nf) {
            const u16* base = sB + (nf * 64 + wn * 16 + lrow) * 64;
            b[nf][0] = *(const bf16x8*)(base + so0);
            b[nf][1] = *(const bf16x8*)(base + so1);
        }
        if (notlast) STAGE_B23(nxt);
        LGKM0; SCHED0;
        PRIO1;
#pragma unroll
        for (int mf = 0; mf < 4; ++mf)
#pragma unroll
            for (int nf = 2; nf < 4; ++nf) {
                acc[mf][nf] = __builtin_amdgcn_mfma_f32_16x16x32_bf16(a[mf][0], b[nf][0], acc[mf][nf], 0, 0, 0);
                acc[mf][nf] = __builtin_amdgcn_mfma_f32_16x16x32_bf16(a[mf][1], b[nf][1], acc[mf][nf], 0, 0, 0);
            }
        PRIO0;
        // ---- phase 2: wait p2-set; read A-hi; issue next p2-set ----
        if (notlast) { VMCNT(6); } else { VMCNT(0); }
        SBAR; SCHED0;
#pragma unroll
        for (int mf = 0; mf < 4; ++mf) {
            const u16* base = sA + (wm * 128 + (mf + 4) * 16 + lrow) * 64;
            a[mf][0] = *(const bf16x8*)(base + so0);
            a[mf][1] = *(const bf16x8*)(base + so1);
        }
        if (notlast) { STAGE_A13(nxt); ADV(); }
        LGKM0; SCHED0;
        PRIO1;
#pragma unroll
        for (int mf = 0; mf < 4; ++mf)
#pragma unroll
            for (int nf = 2; nf < 4; ++nf) {
                acc[mf + 4][nf] = __builtin_amdgcn_mfma_f32_16x16x32_bf16(a[mf][0], b[nf][0], acc[mf + 4][nf], 0, 0, 0);
                acc[mf + 4][nf] = __builtin_amdgcn_mfma_f32_16x16x32_bf16(a[mf][1], b[nf][1], acc[mf + 4][nf], 0, 0, 0);
            }
        PRIO0;
        // ---- phase 3: no reads, no waits (A-hi + B[0..1]) ----
        SBAR;
        PRIO1;
#pragma unroll
        for (int mf = 0; mf < 4; ++mf)
#pragma unroll
            for (int nf = 0; nf < 2; ++nf) {
                acc[mf + 4][nf] = __builtin_amdgcn_mfma_f32_16x16x32_bf16(a[mf][0], b[nf][0], acc[mf + 4][nf], 0, 0, 0);
                acc[mf + 4][nf] = __builtin_amdgcn_mfma_f32_16x16x32_bf16(a[mf][1], b[nf][1], acc[mf + 4][nf], 0, 0, 0);
            }
        PRIO0;
    }

#pragma unroll
    for (int mf = 0; mf < 8; ++mf) {
        const int gr0 = rowbase + wm * 128 + mf * 16 + lq * 4;
#pragma unroll
        for (int nf = 0; nf < 4; ++nf) {
            const int gc = n0 + nf * 64 + wn * 16 + lrow;
#pragma unroll
            for (int r = 0; r < 4; ++r) {
                const int gr = gr0 + r;
                if (gr < rowend) ybuf[(size_t)gr * DIM + gc] = acc[mf][nf][r];
            }
        }
    }
}

// ---------------- combine: out[t] = sum_k w_k * y[slot_k] ----------------
__global__ __launch_bounds__(256) void combine_kernel(const float* __restrict__ ybuf,
                                                      const int* __restrict__ tok_slot,
                                                      const float* __restrict__ tok_w,
                                                      float* __restrict__ out) {
    const int t = blockIdx.x;
    const int d = threadIdx.x * 4;
    const int s0 = tok_slot[t * 3 + 0], s1 = tok_slot[t * 3 + 1], s2 = tok_slot[t * 3 + 2];
    const float w0 = tok_w[t * 3 + 0], w1 = tok_w[t * 3 + 1], w2 = tok_w[t * 3 + 2];
    const float4 a0 = *(const float4*)(ybuf + (size_t)s0 * DIM + d);
    const float4 a1 = *(const float4*)(ybuf + (size_t)s1 * DIM + d);
    const float4 a2 = *(const float4*)(ybuf + (size_t)s2 * DIM + d);
    float4 o;
    o.x = w0 * a0.x + w1 * a1.x + w2 * a2.x;
    o.y = w0 * a0.y + w1 * a1.y + w2 * a2.y;
    o.z = w0 * a0.z + w1 * a1.z + w2 * a2.z;
    o.w = w0 * a0.w + w1 * a1.w + w2 * a2.w;
    *(float4*)(out + (size_t)t * DIM + d) = o;
}

extern "C" void kernel_launch(void* const* d_in, const int* in_sizes, int n_in,
                              void* d_out, int out_size, void* d_ws, size_t ws_size,
                              hipStream_t stream) {
    const float* x   = (const float*)d_in[0];
    const float* rw  = (const float*)d_in[1];
    const float* rb  = (const float*)d_in[2];
    const float* w12 = (const float*)d_in[3];
    const float* w3  = (const float*)d_in[4];
    float* out = (float*)d_out;
    char* ws = (char*)d_ws;

    int*   ctrl       = (int*)(ws + OFF_CTRL);
    u16*   xb         = (u16*)(ws + OFF_XB);
    u16*   w12t       = (u16*)(ws + OFF_W12T);
    u16*   w3t        = (u16*)(ws + OFF_W3T);
    u16*   hidden     = (u16*)(ws + OFF_HID);
    float* ybuf       = (float*)(ws + OFF_Y);
    int*   pair_token = (int*)(ws + OFF_PTOK);
    int*   tok_expert = (int*)(ws + OFF_TE);
    float* tok_w      = (float*)(ws + OFF_TW);
    int*   tok_slot   = (int*)(ws + OFF_TS);

    static bool attr_set = false;
    if (!attr_set) {
        hipFuncSetAttribute((const void*)gemm1_kernel, hipFuncAttributeMaxDynamicSharedMemorySize, 131072);
        hipFuncSetAttribute((const void*)gemm2_kernel, hipFuncAttributeMaxDynamicSharedMemorySize, 131072);
        attr_set = true;
    }

    hipMemsetAsync(ctrl, 0, 256, stream);
    hipMemsetAsync(out + (size_t)T_TOK * DIM, 0, sizeof(float), stream);  // aux slot

    // router (0..1023) + w3 transpose (1024..3071) + w12 transpose (3072..7167)
    prep_kernel<<<PREP_BLOCKS, 256, 0, stream>>>(x, rw, rb, xb, tok_expert, tok_w, ctrl,
                                                 out + (size_t)T_TOK * DIM, w12, w12t, w3, w3t);
    assign_kernel<<<16, 256, 0, stream>>>(tok_expert, ctrl, pair_token, tok_slot);

    gemm1_kernel<<<dim3(HID / 128, 16, NE), 512, 131072, stream>>>(xb, w12t, pair_token, ctrl, hidden);
    gemm2_kernel<<<dim3(DIM / 256, 16, NE), 512, 131072, stream>>>(hidden, w3t, ctrl, ybuf);
    combine_kernel<<<T_TOK, 256, 0, stream>>>(ybuf, tok_slot, tok_w, out);
    (void)in_sizes; (void)n_in; (void)out_size; (void)ws_size;
}

// Round 8
// 792.905 us; speedup vs baseline: 1.0157x; 1.0157x over previous
//
#include <hip/hip_runtime.h>
#include <math.h>

typedef unsigned short u16;
typedef __bf16 bf16x8 __attribute__((ext_vector_type(8)));
typedef float f32x4 __attribute__((ext_vector_type(4)));

#define T_TOK 4096
#define DIM   1024
#define HID   4096
#define NE    8
#define TOPK  3
#define NPAIR 12288   // T_TOK * TOPK

// prep grid: [0,256) w12 panel-transpose blocks | [256,1280) router blocks
#define PREP_RTR_BASE 256
#define PREP_BLOCKS   1280

// ---------------- ws layout (bytes) ----------------
// ctrl ints: [0..7]=ecnt, [16..23]=efill
constexpr size_t OFF_CTRL = 0;
constexpr size_t OFF_XB   = 256;
constexpr size_t OFF_W12T = OFF_XB   + (size_t)T_TOK * DIM * 2;
constexpr size_t OFF_W3T  = OFF_W12T + (size_t)NE * 2 * HID * DIM * 2;
constexpr size_t OFF_HID  = OFF_W3T  + (size_t)NE * DIM * HID * 2;
constexpr size_t OFF_Y    = OFF_HID  + (size_t)NPAIR * HID * 2;
constexpr size_t OFF_PTOK = OFF_Y    + (size_t)NPAIR * DIM * 4;
constexpr size_t OFF_TE   = OFF_PTOK + (size_t)NPAIR * 4;
constexpr size_t OFF_TW   = OFF_TE   + (size_t)T_TOK * TOPK * 4;
constexpr size_t OFF_TS   = OFF_TW   + (size_t)T_TOK * TOPK * 4;

__device__ __forceinline__ u16 f2bf(float f) {
    unsigned u = __builtin_bit_cast(unsigned, f);
    u += 0x7fffu + ((u >> 16) & 1u);   // RNE
    return (u16)(u >> 16);
}

// async global->LDS DMA, 16B per lane; LDS dst = wave-uniform base + lane*16
__device__ __forceinline__ void ld_g2l(const u16* g, u16* l) {
    __builtin_amdgcn_global_load_lds((__attribute__((address_space(1))) unsigned*)(g),
                                     (__attribute__((address_space(3))) unsigned*)(l),
                                     16, 0, 0);
}

// raw sync primitives: raw s_barrier does NOT drain vmcnt (that's the point)
#define VMCNT(N) asm volatile("s_waitcnt vmcnt(" #N ")" ::: "memory")
#define LGKM0  asm volatile("s_waitcnt lgkmcnt(0)" ::: "memory")
#define SBAR   __builtin_amdgcn_s_barrier()
#define SCHED0 __builtin_amdgcn_sched_barrier(0)
#define PRIO1  __builtin_amdgcn_s_setprio(1)
#define PRIO0  __builtin_amdgcn_s_setprio(0)

// quarter staging macros (2 global_load_lds each)
#define STAGE_A02(dst) { ld_g2l(srcA[0], (dst) + (0 * 64 + wave * 8) * 64); \
                         ld_g2l(srcA[2], (dst) + (2 * 64 + wave * 8) * 64); }
#define STAGE_B01(dst) { ld_g2l(srcB[0], (dst) + 16384 + (0 * 64 + wave * 8) * 64); \
                         ld_g2l(srcB[1], (dst) + 16384 + (1 * 64 + wave * 8) * 64); }
#define STAGE_B23(dst) { ld_g2l(srcB[2], (dst) + 16384 + (2 * 64 + wave * 8) * 64); \
                         ld_g2l(srcB[3], (dst) + 16384 + (3 * 64 + wave * 8) * 64); }
#define STAGE_A13(dst) { ld_g2l(srcA[1], (dst) + (1 * 64 + wave * 8) * 64); \
                         ld_g2l(srcA[3], (dst) + (3 * 64 + wave * 8) * 64); }
#define ADV()          { _Pragma("unroll") \
                         for (int r_ = 0; r_ < 4; ++r_) { srcA[r_] += 64; srcB[r_] += 64; } }

// ---------------- transpose-cast 64k x 256n tile, 256 threads ----------------
__device__ __forceinline__ void tc_tile256(const float* __restrict__ inp,
                                           u16* __restrict__ outp,
                                           int K, int N, int n0, int k0, int tid,
                                           u16 (*lt)[72]) {
    const int k = tid >> 2;            // 0..63
    const int cbase = (tid & 3) * 4;   // 0,4,8,12
    const float* row = inp + (size_t)(k0 + k) * N + n0;
#pragma unroll
    for (int j = 0; j < 16; ++j) {
        const int c = cbase + j * 16;
        float4 f = *(const float4*)(row + c);
        lt[c + 0][k] = f2bf(f.x);
        lt[c + 1][k] = f2bf(f.y);
        lt[c + 2][k] = f2bf(f.z);
        lt[c + 3][k] = f2bf(f.w);
    }
    __syncthreads();
    const int rg = tid >> 2;          // 0..63
    const int kc = (tid & 3) * 16;    // 0,16,32,48
#pragma unroll
    for (int g = 0; g < 4; ++g) {
        const int n = g * 64 + rg;
        u16* op = outp + (size_t)(n0 + n) * K + k0 + kc;
        *(uint4*)(op)     = *(const uint4*)(&lt[n][kc]);
        *(uint4*)(op + 8) = *(const uint4*)(&lt[n][kc + 8]);
    }
}

// ---------------- prep: w12 panel transposes + router in ONE launch ----------
// Panel blocks loop over ALL kt for one (expert, 256-col) output panel so the
// panel's writes stay L2-resident and drain page-contiguously (write locality).
__global__ __launch_bounds__(256) void prep_kernel(const float* __restrict__ x,
                                                   const float* __restrict__ rw,
                                                   const float* __restrict__ rb,
                                                   u16* __restrict__ xb,
                                                   int* __restrict__ tok_expert,
                                                   float* __restrict__ tok_w,
                                                   int* __restrict__ ctrl,
                                                   float* __restrict__ aux,
                                                   const float* __restrict__ w12,
                                                   u16* __restrict__ w12t) {
    __shared__ __align__(16) u16 lt[256][72];   // 36 KB
    const int bid = blockIdx.x;
    const int tid = threadIdx.x;

    if (bid < PREP_RTR_BASE) {
        // w12: [DIM][2H] fp32 -> [2H][DIM] bf16. One block per (expert, nt) panel.
        const int z = bid >> 5;            // expert 0..7
        const int nt = bid & 31;           // 0..31
        const float* src = w12 + (size_t)z * DIM * 2 * HID;
        u16* dst = w12t + (size_t)z * DIM * 2 * HID;
        for (int kt = 0; kt < 16; ++kt) {
            tc_tile256(src, dst, DIM, 2 * HID, nt * 256, kt * 64, tid, lt);
            __syncthreads();
        }
        return;
    }

    // ---- router (fused x->bf16 cast, block-level atomics) ----
    int* hist = (int*)&lt[0][0];
    float* auxsh = (float*)&lt[2][0];
    if (tid < NE) hist[tid] = 0;
    if (tid == NE) auxsh[0] = 0.f;
    __syncthreads();

    const int wave = tid >> 6, lane = tid & 63;
    const int t = (bid - PREP_RTR_BASE) * 4 + wave;
    const float* xr = x + (size_t)t * DIM;
    u16* xbr = xb + (size_t)t * DIM;

    float p[NE];
#pragma unroll
    for (int e = 0; e < NE; e++) p[e] = 0.f;
#pragma unroll
    for (int q = 0; q < 4; ++q) {
        const int d = q * 256 + lane * 4;
        float4 f = *(const float4*)(xr + d);
        uint2 v;
        v.x = (unsigned)f2bf(f.x) | ((unsigned)f2bf(f.y) << 16);
        v.y = (unsigned)f2bf(f.z) | ((unsigned)f2bf(f.w) << 16);
        *(uint2*)(xbr + d) = v;
#pragma unroll
        for (int e = 0; e < NE; e++) {
            float4 w = *(const float4*)(rw + e * DIM + d);
            p[e] += f.x * w.x + f.y * w.y + f.z * w.z + f.w * w.w;
        }
    }
#pragma unroll
    for (int e = 0; e < NE; e++) {
#pragma unroll
        for (int off = 32; off; off >>= 1) p[e] += __shfl_down(p[e], off, 64);
    }
    if (lane == 0) {
        float s[NE]; float auxs = 0.f;
#pragma unroll
        for (int e = 0; e < NE; e++) {
            float lg = p[e] + rb[e];
            auxs += lg * lg;
            s[e] = 1.f / (1.f + __expf(-lg));
        }
        atomicAdd(auxsh, auxs);
        unsigned mask = 0; float wsum = 0.f;
        int idxs[TOPK]; float vals[TOPK];
        for (int k = 0; k < TOPK; k++) {
            float best = -1.f; int bi = 0;
            for (int e = 0; e < NE; e++)
                if (!((mask >> e) & 1u) && s[e] > best) { best = s[e]; bi = e; }
            mask |= 1u << bi; idxs[k] = bi; vals[k] = best; wsum += best;
        }
        wsum += 1e-6f;
        for (int k = 0; k < TOPK; k++) {
            tok_expert[t * TOPK + k] = idxs[k];
            tok_w[t * TOPK + k] = vals[k] / wsum;
            atomicAdd(&hist[idxs[k]], 1);
        }
    }
    __syncthreads();
    if (tid < NE) { int h = hist[tid]; if (h) atomicAdd(&ctrl[tid], h); }
    if (tid == NE) atomicAdd(aux, auxsh[0] * (0.01f / 32768.0f));
}

// assign: two-level atomics — per-block LDS histogram, one global reservation
// per expert per block. Slot order within an expert is a permutation;
// all consumers are permutation-invariant.
__global__ __launch_bounds__(256) void assign_kernel(const int* __restrict__ tok_expert,
                                                     int* __restrict__ ctrl,
                                                     int* __restrict__ pair_token,
                                                     int* __restrict__ tok_slot) {
    __shared__ int soff[NE];   // global expert start (prefix of counts)
    __shared__ int hist[NE];   // this block's per-expert count
    __shared__ int base[NE];   // this block's reserved base within expert
    const int tid = threadIdx.x;
    if (tid < NE) {
        int acc = 0;
        for (int i = 0; i < tid; ++i) acc += ctrl[i];
        soff[tid] = acc;
        hist[tid] = 0;
    }
    __syncthreads();
    const int t = blockIdx.x * blockDim.x + tid;
    int e[TOPK], p[TOPK];
#pragma unroll
    for (int k = 0; k < TOPK; k++) {
        e[k] = tok_expert[t * TOPK + k];
        p[k] = atomicAdd(&hist[e[k]], 1);
    }
    __syncthreads();
    if (tid < NE && hist[tid]) base[tid] = atomicAdd(&ctrl[16 + tid], hist[tid]);
    __syncthreads();
#pragma unroll
    for (int k = 0; k < TOPK; k++) {
        const int slot = soff[e[k]] + base[e[k]] + p[k];
        pair_token[slot] = t;
        tok_slot[t * TOPK + k] = slot;
    }
}

// ---------------- GEMM1 (+ w3 transpose plane z==8) ----------------
// z<8: round-2 schedule verbatim (best measured 236 us / MfmaUtil 41.5%).
// z==8: w3 [HID][DIM] fp32 -> [DIM][HID] bf16 transpose-cast; 512 blocks x 4 kt,
// dispatched after all gemm1 blocks (z slowest) -> fills gemm1's tail bubbles.
// gemm2 (next launch) orders after this kernel, so w3t is ready.
__global__ __launch_bounds__(512, 2) void gemm1_kernel(const u16* __restrict__ xb,
                                                       const u16* __restrict__ w12t,
                                                       const int* __restrict__ pair_token,
                                                       const int* __restrict__ ctrl,
                                                       u16* __restrict__ hidden,
                                                       const float* __restrict__ w3,
                                                       u16* __restrict__ w3t) {
    extern __shared__ __align__(16) u16 lds[];   // 128 KiB dynamic
    const int tid = threadIdx.x;

    if (blockIdx.z == 8) {
        // ---- w3 transpose-cast, 512 threads, 4 consecutive kt per block ----
        u16 (*lt)[72] = (u16(*)[72])lds;         // 36 KB of the dynamic LDS
        const int t9 = blockIdx.y * 32 + blockIdx.x;   // 0..511
        const int e9 = t9 >> 6;
        const int r9 = t9 & 63;
        const int nt = r9 >> 4;            // 0..3
        const int ktg = r9 & 15;           // 0..15
        const float* src = w3 + (size_t)e9 * HID * DIM;
        u16* dst = w3t + (size_t)e9 * HID * DIM;
        const int n0 = nt * 256;
        for (int i = 0; i < 4; ++i) {
            const int k0 = (ktg * 4 + i) * 64;
            const int kr = tid >> 3;           // 0..63, 8 threads/row
            const int cb = (tid & 7) * 4;
            const float* row = src + (size_t)(k0 + kr) * DIM + n0;
#pragma unroll
            for (int j = 0; j < 8; ++j) {
                const int c = cb + j * 32;
                float4 f = *(const float4*)(row + c);
                lt[c + 0][kr] = f2bf(f.x);
                lt[c + 1][kr] = f2bf(f.y);
                lt[c + 2][kr] = f2bf(f.z);
                lt[c + 3][kr] = f2bf(f.w);
            }
            __syncthreads();
            const int n = tid >> 1;            // 0..255, 2 threads/row
            const int kc = (tid & 1) * 32;
            u16* op = dst + (size_t)(n0 + n) * HID + k0 + kc;
            *(uint4*)(op)      = *(const uint4*)(&lt[n][kc]);
            *(uint4*)(op + 8)  = *(const uint4*)(&lt[n][kc + 8]);
            *(uint4*)(op + 16) = *(const uint4*)(&lt[n][kc + 16]);
            *(uint4*)(op + 24) = *(const uint4*)(&lt[n][kc + 24]);
            __syncthreads();
        }
        return;
    }

    const int e = blockIdx.z;
    const int cnt = ctrl[e];
    if ((int)blockIdx.y * 256 >= cnt) return;
    int off = 0;
    for (int i = 0; i < e; ++i) off += ctrl[i];
    const int rowbase = off + blockIdx.y * 256;
    const int rowend = off + cnt;
    const int n0 = blockIdx.x * 128;   // col base within each half

    const int wave = tid >> 6, lane = tid & 63;
    const int srow = tid >> 3;                       // 0..63 row-in-round
    const int scol = ((tid & 7) ^ (srow & 7)) * 8;   // pre-swizzled global col

    const u16* srcA[4];
    const u16* srcB[4];
#pragma unroll
    for (int r = 0; r < 4; ++r) {
        int sr = rowbase + r * 64 + srow;
        int tok = (sr < rowend) ? pair_token[sr] : 0;
        srcA[r] = xb + (size_t)tok * DIM + scol;
    }
#pragma unroll
    for (int r = 0; r < 2; ++r) {
        srcB[r]     = w12t + ((size_t)e * 2 * HID + n0 + r * 64 + srow) * DIM + scol; // w1
        srcB[r + 2] = srcB[r] + (size_t)HID * DIM;                                    // w2
    }

    const int wm = wave >> 2, wn = wave & 3;
    const int lrow = lane & 15, lq = lane >> 4, xm = lrow & 7;
    const int so0 = ((lq ^ xm) << 3);
    const int so1 = (((4 | lq) ^ xm) << 3);

    f32x4 acc0[8][2], acc1[8][2];
#pragma unroll
    for (int mf = 0; mf < 8; ++mf)
#pragma unroll
        for (int nf = 0; nf < 2; ++nf) { acc0[mf][nf] = (f32x4)0.f; acc1[mf][nf] = (f32x4)0.f; }

    // prologue: stage K-tile 0 in queue order [p0-set(4), p1-set(2), p2-set(2)]
    STAGE_A02(lds); STAGE_B01(lds);
    STAGE_B23(lds);
    STAGE_A13(lds);
    ADV();

    const int NT = DIM / 64;   // 16
    for (int kt = 0; kt < NT; ++kt) {
        u16* cur = lds + (kt & 1) * 32768;
        u16* nxt = lds + ((kt & 1) ^ 1) * 32768;
        const u16* sA = cur;
        const u16* sB = cur + 16384;
        const bool notlast = (kt < NT - 1);

        bf16x8 a[4][2], b0[2][2], b1[2][2];
        // ---- phase 0: wait p0-set; read A-lo + B0; issue next p0-set ----
        VMCNT(4); SBAR; SCHED0;
#pragma unroll
        for (int mf = 0; mf < 4; ++mf) {
            const u16* base = sA + (wm * 128 + mf * 16 + lrow) * 64;
            a[mf][0] = *(const bf16x8*)(base + so0);
            a[mf][1] = *(const bf16x8*)(base + so1);
        }
#pragma unroll
        for (int nf = 0; nf < 2; ++nf) {
            const u16* base = sB + (wn * 32 + nf * 16 + lrow) * 64;
            b0[nf][0] = *(const bf16x8*)(base + so0);
            b0[nf][1] = *(const bf16x8*)(base + so1);
        }
        if (notlast) { STAGE_A02(nxt); STAGE_B01(nxt); }
        LGKM0; SCHED0;
        PRIO1;
#pragma unroll
        for (int mf = 0; mf < 4; ++mf)
#pragma unroll
            for (int nf = 0; nf < 2; ++nf) {
                acc0[mf][nf] = __builtin_amdgcn_mfma_f32_16x16x32_bf16(a[mf][0], b0[nf][0], acc0[mf][nf], 0, 0, 0);
                acc0[mf][nf] = __builtin_amdgcn_mfma_f32_16x16x32_bf16(a[mf][1], b0[nf][1], acc0[mf][nf], 0, 0, 0);
            }
        PRIO0;
        // ---- phase 1: wait p1-set; read B1; issue next p1-set ----
        if (notlast) { VMCNT(6); } else { VMCNT(2); }
        SBAR; SCHED0;
#pragma unroll
        for (int nf = 0; nf < 2; ++nf) {
            const u16* base = sB + 128 * 64 + (wn * 32 + nf * 16 + lrow) * 64;
            b1[nf][0] = *(const bf16x8*)(base + so0);
            b1[nf][1] = *(const bf16x8*)(base + so1);
        }
        if (notlast) STAGE_B23(nxt);
        LGKM0; SCHED0;
        PRIO1;
#pragma unroll
        for (int mf = 0; mf < 4; ++mf)
#pragma unroll
            for (int nf = 0; nf < 2; ++nf) {
                acc1[mf][nf] = __builtin_amdgcn_mfma_f32_16x16x32_bf16(a[mf][0], b1[nf][0], acc1[mf][nf], 0, 0, 0);
                acc1[mf][nf] = __builtin_amdgcn_mfma_f32_16x16x32_bf16(a[mf][1], b1[nf][1], acc1[mf][nf], 0, 0, 0);
            }
        PRIO0;
        // ---- phase 2: wait p2-set; read A-hi; issue next p2-set ----
        if (notlast) { VMCNT(6); } else { VMCNT(0); }
        SBAR; SCHED0;
#pragma unroll
        for (int mf = 0; mf < 4; ++mf) {
            const u16* base = sA + (wm * 128 + (mf + 4) * 16 + lrow) * 64;
            a[mf][0] = *(const bf16x8*)(base + so0);
            a[mf][1] = *(const bf16x8*)(base + so1);
        }
        if (notlast) { STAGE_A13(nxt); ADV(); }
        LGKM0; SCHED0;
        PRIO1;
#pragma unroll
        for (int mf = 0; mf < 4; ++mf)
#pragma unroll
            for (int nf = 0; nf < 2; ++nf) {
                acc1[mf + 4][nf] = __builtin_amdgcn_mfma_f32_16x16x32_bf16(a[mf][0], b1[nf][0], acc1[mf + 4][nf], 0, 0, 0);
                acc1[mf + 4][nf] = __builtin_amdgcn_mfma_f32_16x16x32_bf16(a[mf][1], b1[nf][1], acc1[mf + 4][nf], 0, 0, 0);
            }
        PRIO0;
        // ---- phase 3: no reads, no waits (reuse A-hi + B0) ----
        SBAR;
        PRIO1;
#pragma unroll
        for (int mf = 0; mf < 4; ++mf)
#pragma unroll
            for (int nf = 0; nf < 2; ++nf) {
                acc0[mf + 4][nf] = __builtin_amdgcn_mfma_f32_16x16x32_bf16(a[mf][0], b0[nf][0], acc0[mf + 4][nf], 0, 0, 0);
                acc0[mf + 4][nf] = __builtin_amdgcn_mfma_f32_16x16x32_bf16(a[mf][1], b0[nf][1], acc0[mf + 4][nf], 0, 0, 0);
            }
        PRIO0;
    }

#pragma unroll
    for (int mf = 0; mf < 8; ++mf) {
        const int gr0 = rowbase + wm * 128 + mf * 16 + lq * 4;
#pragma unroll
        for (int nf = 0; nf < 2; ++nf) {
            const int gc = n0 + wn * 32 + nf * 16 + lrow;
#pragma unroll
            for (int r = 0; r < 4; ++r) {
                const int gr = gr0 + r;
                if (gr < rowend) {
                    float x1 = acc0[mf][nf][r], x2 = acc1[mf][nf][r];
                    float h = x1 / (1.f + __expf(-x1)) * x2;
                    hidden[(size_t)gr * HID + gc] = f2bf(h);
                }
            }
        }
    }
}

// ---------------- GEMM2: y = hidden @ w3 ----------------
// 256x256 tile, BK=64, 8 waves (2Mx4N) — round-2 wall schedule:
// counted vmcnt 4/6/6, lgkm wall + setprio around each MFMA cluster.
__global__ __launch_bounds__(512, 2) void gemm2_kernel(const u16* __restrict__ hidden,
                                                       const u16* __restrict__ w3t,
                                                       const int* __restrict__ ctrl,
                                                       float* __restrict__ ybuf) {
    const int e = blockIdx.z;
    const int cnt = ctrl[e];
    if ((int)blockIdx.y * 256 >= cnt) return;
    int off = 0;
    for (int i = 0; i < e; ++i) off += ctrl[i];
    const int rowbase = off + blockIdx.y * 256;
    const int rowend = off + cnt;
    const int n0 = blockIdx.x * 256;

    extern __shared__ __align__(16) u16 lds[];

    const int tid = threadIdx.x;
    const int wave = tid >> 6, lane = tid & 63;
    const int srow = tid >> 3;
    const int scol = ((tid & 7) ^ (srow & 7)) * 8;

    const u16* srcA[4];
    const u16* srcB[4];
#pragma unroll
    for (int r = 0; r < 4; ++r) {
        int sr = rowbase + r * 64 + srow;
        if (sr > NPAIR - 1) sr = NPAIR - 1;
        srcA[r] = hidden + (size_t)sr * HID + scol;
        srcB[r] = w3t + ((size_t)e * DIM + n0 + r * 64 + srow) * HID + scol;
    }

    const int wm = wave >> 2, wn = wave & 3;
    const int lrow = lane & 15, lq = lane >> 4, xm = lrow & 7;
    const int so0 = ((lq ^ xm) << 3);
    const int so1 = (((4 | lq) ^ xm) << 3);

    f32x4 acc[8][4];
#pragma unroll
    for (int mf = 0; mf < 8; ++mf)
#pragma unroll
        for (int nf = 0; nf < 4; ++nf) acc[mf][nf] = (f32x4)0.f;

    STAGE_A02(lds); STAGE_B01(lds);
    STAGE_B23(lds);
    STAGE_A13(lds);
    ADV();

    const int NT = HID / 64;   // 64
    for (int kt = 0; kt < NT; ++kt) {
        u16* cur = lds + (kt & 1) * 32768;
        u16* nxt = lds + ((kt & 1) ^ 1) * 32768;
        const u16* sA = cur;
        const u16* sB = cur + 16384;
        const bool notlast = (kt < NT - 1);

        bf16x8 a[4][2], b[4][2];
        // ---- phase 0: wait p0-set; read A-lo + B[0..1]; issue next p0-set ----
        VMCNT(4); SBAR; SCHED0;
#pragma unroll
        for (int mf = 0; mf < 4; ++mf) {
            const u16* base = sA + (wm * 128 + mf * 16 + lrow) * 64;
            a[mf][0] = *(const bf16x8*)(base + so0);
            a[mf][1] = *(const bf16x8*)(base + so1);
        }
#pragma unroll
        for (int nf = 0; nf < 2; ++nf) {
            const u16* base = sB + (nf * 64 + wn * 16 + lrow) * 64;
            b[nf][0] = *(const bf16x8*)(base + so0);
            b[nf][1] = *(const bf16x8*)(base + so1);
        }
        if (notlast) { STAGE_A02(nxt); STAGE_B01(nxt); }
        LGKM0; SCHED0;
        PRIO1;
#pragma unroll
        for (int mf = 0; mf < 4; ++mf)
#pragma unroll
            for (int nf = 0; nf < 2; ++nf) {
                acc[mf][nf] = __builtin_amdgcn_mfma_f32_16x16x32_bf16(a[mf][0], b[nf][0], acc[mf][nf], 0, 0, 0);
                acc[mf][nf] = __builtin_amdgcn_mfma_f32_16x16x32_bf16(a[mf][1], b[nf][1], acc[mf][nf], 0, 0, 0);
            }
        PRIO0;
        // ---- phase 1: wait p1-set; read B[2..3]; issue next p1-set ----
        if (notlast) { VMCNT(6); } else { VMCNT(2); }
        SBAR; SCHED0;
#pragma unroll
        for (int nf = 2; nf < 4; ++nf) {
            const u16* base = sB + (nf * 64 + wn * 16 + lrow) * 64;
            b[nf][0] = *(const bf16x8*)(base + so0);
            b[nf][1] = *(const bf16x8*)(base + so1);
        }
        if (notlast) STAGE_B23(nxt);
        LGKM0; SCHED0;
        PRIO1;
#pragma unroll
        for (int mf = 0; mf < 4; ++mf)
#pragma unroll
            for (int nf = 2; nf < 4; ++nf) {
                acc[mf][nf] = __builtin_amdgcn_mfma_f32_16x16x32_bf16(a[mf][0], b[nf][0], acc[mf][nf], 0, 0, 0);
                acc[mf][nf] = __builtin_amdgcn_mfma_f32_16x16x32_bf16(a[mf][1], b[nf][1], acc[mf][nf], 0, 0, 0);
            }
        PRIO0;
        // ---- phase 2: wait p2-set; read A-hi; issue next p2-set ----
        if (notlast) { VMCNT(6); } else { VMCNT(0); }
        SBAR; SCHED0;
#pragma unroll
        for (int mf = 0; mf < 4; ++mf) {
            const u16* base = sA + (wm * 128 + (mf + 4) * 16 + lrow) * 64;
            a[mf][0] = *(const bf16x8*)(base + so0);
            a[mf][1] = *(const bf16x8*)(base + so1);
        }
        if (notlast) { STAGE_A13(nxt); ADV(); }
        LGKM0; SCHED0;
        PRIO1;
#pragma unroll
        for (int mf = 0; mf < 4; ++mf)
#pragma unroll
            for (int nf = 2; nf < 4; ++nf) {
                acc[mf + 4][nf] = __builtin_amdgcn_mfma_f32_16x16x32_bf16(a[mf][0], b[nf][0], acc[mf + 4][nf], 0, 0, 0);
                acc[mf + 4][nf] = __builtin_amdgcn_mfma_f32_16x16x32_bf16(a[mf][1], b[nf][1], acc[mf + 4][nf], 0, 0, 0);
            }
        PRIO0;
        // ---- phase 3: no reads, no waits (A-hi + B[0..1]) ----
        SBAR;
        PRIO1;
#pragma unroll
        for (int mf = 0; mf < 4; ++mf)
#pragma unroll
            for (int nf = 0; nf < 2; ++nf) {
                acc[mf + 4][nf] = __builtin_amdgcn_mfma_f32_16x16x32_bf16(a[mf][0], b[nf][0], acc[mf + 4][nf], 0, 0, 0);
                acc[mf + 4][nf] = __builtin_amdgcn_mfma_f32_16x16x32_bf16(a[mf][1], b[nf][1], acc[mf + 4][nf], 0, 0, 0);
            }
        PRIO0;
    }

#pragma unroll
    for (int mf = 0; mf < 8; ++mf) {
        const int gr0 = rowbase + wm * 128 + mf * 16 + lq * 4;
#pragma unroll
        for (int nf = 0; nf < 4; ++nf) {
            const int gc = n0 + nf * 64 + wn * 16 + lrow;
#pragma unroll
            for (int r = 0; r < 4; ++r) {
                const int gr = gr0 + r;
                if (gr < rowend) ybuf[(size_t)gr * DIM + gc] = acc[mf][nf][r];
            }
        }
    }
}

// ---------------- combine: out[t] = sum_k w_k * y[slot_k] ----------------
__global__ __launch_bounds__(256) void combine_kernel(const float* __restrict__ ybuf,
                                                      const int* __restrict__ tok_slot,
                                                      const float* __restrict__ tok_w,
                                                      float* __restrict__ out) {
    const int t = blockIdx.x;
    const int d = threadIdx.x * 4;
    const int s0 = tok_slot[t * 3 + 0], s1 = tok_slot[t * 3 + 1], s2 = tok_slot[t * 3 + 2];
    const float w0 = tok_w[t * 3 + 0], w1 = tok_w[t * 3 + 1], w2 = tok_w[t * 3 + 2];
    const float4 a0 = *(const float4*)(ybuf + (size_t)s0 * DIM + d);
    const float4 a1 = *(const float4*)(ybuf + (size_t)s1 * DIM + d);
    const float4 a2 = *(const float4*)(ybuf + (size_t)s2 * DIM + d);
    float4 o;
    o.x = w0 * a0.x + w1 * a1.x + w2 * a2.x;
    o.y = w0 * a0.y + w1 * a1.y + w2 * a2.y;
    o.z = w0 * a0.z + w1 * a1.z + w2 * a2.z;
    o.w = w0 * a0.w + w1 * a1.w + w2 * a2.w;
    *(float4*)(out + (size_t)t * DIM + d) = o;
}

extern "C" void kernel_launch(void* const* d_in, const int* in_sizes, int n_in,
                              void* d_out, int out_size, void* d_ws, size_t ws_size,
                              hipStream_t stream) {
    const float* x   = (const float*)d_in[0];
    const float* rw  = (const float*)d_in[1];
    const float* rb  = (const float*)d_in[2];
    const float* w12 = (const float*)d_in[3];
    const float* w3  = (const float*)d_in[4];
    float* out = (float*)d_out;
    char* ws = (char*)d_ws;

    int*   ctrl       = (int*)(ws + OFF_CTRL);
    u16*   xb         = (u16*)(ws + OFF_XB);
    u16*   w12t       = (u16*)(ws + OFF_W12T);
    u16*   w3t        = (u16*)(ws + OFF_W3T);
    u16*   hidden     = (u16*)(ws + OFF_HID);
    float* ybuf       = (float*)(ws + OFF_Y);
    int*   pair_token = (int*)(ws + OFF_PTOK);
    int*   tok_expert = (int*)(ws + OFF_TE);
    float* tok_w      = (float*)(ws + OFF_TW);
    int*   tok_slot   = (int*)(ws + OFF_TS);

    static bool attr_set = false;
    if (!attr_set) {
        hipFuncSetAttribute((const void*)gemm1_kernel, hipFuncAttributeMaxDynamicSharedMemorySize, 131072);
        hipFuncSetAttribute((const void*)gemm2_kernel, hipFuncAttributeMaxDynamicSharedMemorySize, 131072);
        attr_set = true;
    }

    hipMemsetAsync(ctrl, 0, 256, stream);
    hipMemsetAsync(out + (size_t)T_TOK * DIM, 0, sizeof(float), stream);  // aux slot

    // w12 panels (0..255, long-running, dispatch first) + router (256..1279)
    prep_kernel<<<PREP_BLOCKS, 256, 0, stream>>>(x, rw, rb, xb, tok_expert, tok_w, ctrl,
                                                 out + (size_t)T_TOK * DIM, w12, w12t);
    assign_kernel<<<16, 256, 0, stream>>>(tok_expert, ctrl, pair_token, tok_slot);

    // z<8: gemm1; z==8: w3 transpose (fills gemm1 tail; gemm2 orders after)
    gemm1_kernel<<<dim3(HID / 128, 16, 9), 512, 131072, stream>>>(xb, w12t, pair_token, ctrl,
                                                                  hidden, w3, w3t);
    gemm2_kernel<<<dim3(DIM / 256, 16, NE), 512, 131072, stream>>>(hidden, w3t, ctrl, ybuf);
    combine_kernel<<<T_TOK, 256, 0, stream>>>(ybuf, tok_slot, tok_w, out);
    (void)in_sizes; (void)n_in; (void)out_size; (void)ws_size;
}